// Round 6
// baseline (13679.738 us; speedup 1.0000x reference)
//
#include <hip/hip_runtime.h>

#define IDIM 128
#define ODIM 128
#define NH   8
#define DQH  32      // 2*ODIM/NH
#define EPSV 1e-10f
#define GEMM_GX 120

typedef __attribute__((ext_vector_type(8))) short bf16x8;
typedef __attribute__((ext_vector_type(4))) float f32x4;

__device__ __forceinline__ float leaky(float w) { return w > 0.f ? w : 0.2f * w; }

// order-preserving float <-> u32 encoding for atomicMax
__device__ __forceinline__ unsigned encf(float f) {
  unsigned b = __float_as_uint(f);
  return (b & 0x80000000u) ? ~b : (b | 0x80000000u);
}
__device__ __forceinline__ float decf(unsigned e) {
  unsigned b = (e & 0x80000000u) ? (e & 0x7fffffffu) : ~e;
  return __uint_as_float(b);
}

__device__ __forceinline__ unsigned short f2bf(float f) {  // RNE
  unsigned u = __float_as_uint(f);
  u = u + 0x7fffu + ((u >> 16) & 1u);
  return (unsigned short)(u >> 16);
}
__device__ __forceinline__ float bf2f(unsigned short h) {
  return __uint_as_float(((unsigned)h) << 16);
}

// ---------------------------------------------------------------------------
// split-bf16 conversion: hi = bf16(v), lo = bf16(v - hi)   (vectorized x4)
// ---------------------------------------------------------------------------
__global__ __launch_bounds__(256) void k_cvt(
    const float* __restrict__ in, ushort4* __restrict__ hi,
    ushort4* __restrict__ lo, int total4) {
  int i = blockIdx.x * 256 + threadIdx.x;
  if (i >= total4) return;
  float4 v = ((const float4*)in)[i];
  ushort4 h, l;
  h.x = f2bf(v.x); l.x = f2bf(v.x - bf2f(h.x));
  h.y = f2bf(v.y); l.y = f2bf(v.y - bf2f(h.y));
  h.z = f2bf(v.z); l.z = f2bf(v.z - bf2f(h.z));
  h.w = f2bf(v.w); l.w = f2bf(v.w - bf2f(h.w));
  hi[i] = h; lo[i] = l;
}

// ---------------------------------------------------------------------------
// MFMA GEMM: hidden[ry][n][o] = sum_d x[n][d] * W[r0+ry][o][d]
// 3-term split-bf16: xh*Wh + xh*Wl + xl*Wh  (error ~2^-17, effectively f32)
// block = 256 (4 waves); W[r] (hi+lo) staged in LDS lane-ordered (64 KB);
// wave computes 16 nodes x 128 outs per tile iteration.
// ---------------------------------------------------------------------------
__global__ __launch_bounds__(256) void k_mfma_hidden(
    const unsigned short* __restrict__ xhi, const unsigned short* __restrict__ xlo,
    const unsigned short* __restrict__ whi, const unsigned short* __restrict__ wlo,
    float* __restrict__ hidden, int Nn, int r0) {
  const int ry = blockIdx.y;
  const int r  = r0 + ry;
  __shared__ unsigned short WL[2][4][8][64][8];  // [hi/lo][kstep][otile][lane][8] = 64 KB
  const int t = threadIdx.x;

  // stage W (hi+lo) into lane-ordered LDS: entry (half,ks,ot,lane) <- W[ot*16+(lane&15)][ks*32+(lane>>4)*8 ..+7]
  for (int idx = t; idx < 2 * 4 * 8 * 64; idx += 256) {
    int half = idx >> 11;
    int rem  = idx & 2047;
    int ks   = rem >> 9;
    int ot   = (rem >> 6) & 7;
    int ln   = rem & 63;
    int orow = ot * 16 + (ln & 15);
    int kcol = ks * 32 + (ln >> 4) * 8;
    const unsigned short* src =
        (half ? wlo : whi) + (size_t)r * ODIM * IDIM + orow * IDIM + kcol;
    *(ulonglong2*)(&WL[half][ks][ot][ln][0]) = *(const ulonglong2*)src;
  }
  __syncthreads();

  const int wave = t >> 6, lane = t & 63;
  const int lrow = lane & 15, lk8 = lane >> 4;

  for (int tile = blockIdx.x; tile * 64 < Nn; tile += GEMM_GX) {
    int n0 = tile * 64 + wave * 16;
    int nrow = n0 + lrow; if (nrow >= Nn) nrow = Nn - 1;   // clamp; write guarded
    const unsigned short* xh = xhi + (size_t)nrow * IDIM + lk8 * 8;
    const unsigned short* xl = xlo + (size_t)nrow * IDIM + lk8 * 8;

    f32x4 acc[8] = {};
    #pragma unroll
    for (int ks = 0; ks < 4; ++ks) {
      bf16x8 ah = *(const bf16x8*)(xh + ks * 32);
      bf16x8 al = *(const bf16x8*)(xl + ks * 32);
      #pragma unroll
      for (int ot = 0; ot < 8; ++ot) {
        bf16x8 bh = *(const bf16x8*)(&WL[0][ks][ot][lane][0]);
        bf16x8 bl = *(const bf16x8*)(&WL[1][ks][ot][lane][0]);
        acc[ot] = __builtin_amdgcn_mfma_f32_16x16x32_bf16(ah, bh, acc[ot], 0, 0, 0);
        acc[ot] = __builtin_amdgcn_mfma_f32_16x16x32_bf16(ah, bl, acc[ot], 0, 0, 0);
        acc[ot] = __builtin_amdgcn_mfma_f32_16x16x32_bf16(al, bh, acc[ot], 0, 0, 0);
      }
    }
    // C/D layout (m89/m91): col = lane&15, row = (lane>>4)*4 + reg
    float* hbase = hidden + ((size_t)ry * Nn + n0) * ODIM;
    #pragma unroll
    for (int ot = 0; ot < 8; ++ot) {
      #pragma unroll
      for (int reg = 0; reg < 4; ++reg) {
        int nodeo = lk8 * 4 + reg;
        if (n0 + nodeo < Nn)
          hbase[(size_t)nodeo * ODIM + ot * 16 + lrow] = acc[ot][reg];
      }
    }
  }
}

// ---------------------------------------------------------------------------
// qWe[r][h][d] = sum_j query[r,h,2j]   * W[r][16h+j][d]   (qWo: odd lanes)
// ---------------------------------------------------------------------------
__global__ __launch_bounds__(256) void k_qw(
    const float* __restrict__ W, const float* __restrict__ query,
    float* __restrict__ qWe, float* __restrict__ qWo, int total) {
  int idx = blockIdx.x * 256 + threadIdx.x;
  if (idx >= total) return;
  int d  = idx & 127;
  int rh = idx >> 7;
  int r = rh >> 3, h = rh & 7;
  const float* q  = query + (size_t)rh * DQH;
  const float* Wb = W + ((size_t)r * ODIM + h * 16) * IDIM + d;
  float se = 0.f, so = 0.f;
  #pragma unroll
  for (int j = 0; j < 16; ++j) {
    float wv = Wb[(size_t)j * IDIM];
    se += q[2 * j] * wv;
    so += q[2 * j + 1] * wv;
  }
  qWe[idx] = se;
  qWo[idx] = so;
}

// ---------------------------------------------------------------------------
// A[r][n][h] = qWe[r][h][:] . x[n][:]   ;   B likewise with qWo
// ---------------------------------------------------------------------------
__global__ __launch_bounds__(256) void k_AB(
    const float* __restrict__ x, const float* __restrict__ qWe,
    const float* __restrict__ qWo, float* __restrict__ A, float* __restrict__ B,
    int N, int Rp1) {
  __shared__ float xs[16][132];
  const int n0 = blockIdx.x * 16;
  const int t = threadIdx.x;
  for (int i = t; i < 16 * 32; i += 256) {
    int node = i >> 5, c4 = i & 31;
    int n = n0 + node;
    float4 v = make_float4(0.f, 0.f, 0.f, 0.f);
    if (n < N) v = *(const float4*)(x + (size_t)n * IDIM + c4 * 4);
    *(float4*)(&xs[node][c4 * 4]) = v;
  }
  __syncthreads();
  const int node = t >> 4;
  const int lane = t & 15;
  const int n = n0 + node;
  if (n >= N) return;
  const float4* xr = (const float4*)(&xs[node][0]);
  const int nrh = Rp1 * NH;
  for (int rh = lane; rh < nrh; rh += 16) {
    const float4* qe = (const float4*)(qWe + (size_t)rh * IDIM);
    const float4* qo = (const float4*)(qWo + (size_t)rh * IDIM);
    float se0 = 0, se1 = 0, se2 = 0, se3 = 0;
    float so0 = 0, so1 = 0, so2 = 0, so3 = 0;
    #pragma unroll
    for (int d4 = 0; d4 < 32; ++d4) {
      float4 xv = xr[d4], ev = qe[d4], ov = qo[d4];
      se0 += ev.x * xv.x; se1 += ev.y * xv.y; se2 += ev.z * xv.z; se3 += ev.w * xv.w;
      so0 += ov.x * xv.x; so1 += ov.y * xv.y; so2 += ov.z * xv.z; so3 += ov.w * xv.w;
    }
    int r = rh >> 3, h = rh & 7;
    A[((size_t)r * N + n) * NH + h] = (se0 + se1) + (se2 + se3);
    B[((size_t)r * N + n) * NH + h] = (so0 + so1) + (so2 + so3);
  }
}

// ---------------------------------------------------------------------------
// zero out / wmax / normsum / cnt
// ---------------------------------------------------------------------------
__global__ __launch_bounds__(256) void k_init(
    float* __restrict__ out, unsigned* __restrict__ wmax,
    float* __restrict__ normsum, float* __restrict__ cnt, int N) {
  int tid = blockIdx.x * 256 + threadIdx.x;
  if (tid < N * ODIM) out[tid] = 0.f;
  if (tid < N * NH) { wmax[tid] = 0u; normsum[tid] = 0.f; }
  if (tid < N) cnt[tid] = 0.f;
}

// ---------------------------------------------------------------------------
// per edge: w[h] = leaky(A[r][s][h] + B[r][d][h]); wmax atomicMax; cnt += 1
// ---------------------------------------------------------------------------
__global__ __launch_bounds__(256) void k_wmax(
    const int* __restrict__ el, const float* __restrict__ A,
    const float* __restrict__ B, unsigned* __restrict__ wmax,
    float* __restrict__ cnt, int E, int Etot, int N, int selfRel) {
  int e = blockIdx.x * 256 + threadIdx.x;
  if (e >= Etot) return;
  int s, d, r;
  if (e < E) { s = el[3 * e]; d = el[3 * e + 1]; r = el[3 * e + 2]; }
  else       { s = d = e - E; r = selfRel; }
  const float4* Ap = (const float4*)(A + ((size_t)r * N + s) * NH);
  const float4* Bp = (const float4*)(B + ((size_t)r * N + d) * NH);
  float4 a0 = Ap[0], a1 = Ap[1], b0 = Bp[0], b1 = Bp[1];
  unsigned* wm = wmax + (size_t)d * NH;
  atomicMax(&wm[0], encf(leaky(a0.x + b0.x)));
  atomicMax(&wm[1], encf(leaky(a0.y + b0.y)));
  atomicMax(&wm[2], encf(leaky(a0.z + b0.z)));
  atomicMax(&wm[3], encf(leaky(a0.w + b0.w)));
  atomicMax(&wm[4], encf(leaky(a1.x + b1.x)));
  atomicMax(&wm[5], encf(leaky(a1.y + b1.y)));
  atomicMax(&wm[6], encf(leaky(a1.z + b1.z)));
  atomicMax(&wm[7], encf(leaky(a1.w + b1.w)));
  atomicAdd(&cnt[d], 1.0f);
}

// ---------------------------------------------------------------------------
// per edge: att[h] = exp(w - wmax)*ew ; normsum[d][h] += att[h]
// ---------------------------------------------------------------------------
__global__ __launch_bounds__(256) void k_norm(
    const int* __restrict__ el, const float* __restrict__ ew,
    const float* __restrict__ A, const float* __restrict__ B,
    const unsigned* __restrict__ wmax, float* __restrict__ normsum,
    int E, int Etot, int N, int selfRel) {
  int e = blockIdx.x * 256 + threadIdx.x;
  if (e >= Etot) return;
  int s, d, r; float ewv;
  if (e < E) { s = el[3 * e]; d = el[3 * e + 1]; r = el[3 * e + 2]; ewv = ew[e]; }
  else       { s = d = e - E; r = selfRel; ewv = 1.0f; }
  const float4* Ap = (const float4*)(A + ((size_t)r * N + s) * NH);
  const float4* Bp = (const float4*)(B + ((size_t)r * N + d) * NH);
  float4 a0 = Ap[0], a1 = Ap[1], b0 = Bp[0], b1 = Bp[1];
  const unsigned* wm = wmax + (size_t)d * NH;
  float* ns = normsum + (size_t)d * NH;
  float wv[8] = {a0.x + b0.x, a0.y + b0.y, a0.z + b0.z, a0.w + b0.w,
                 a1.x + b1.x, a1.y + b1.y, a1.z + b1.z, a1.w + b1.w};
  #pragma unroll
  for (int h = 0; h < 8; ++h) {
    float att = expf(leaky(wv[h]) - decf(wm[h])) * ewv;
    atomicAdd(&ns[h], att);
  }
}

// ---------------------------------------------------------------------------
// scatter: thread = (edge, head). att' computed once per head; 16 atomics.
// ---------------------------------------------------------------------------
__global__ __launch_bounds__(256) void k_scatter(
    const int* __restrict__ el, const float* __restrict__ ew,
    const float* __restrict__ A, const float* __restrict__ B,
    const unsigned* __restrict__ wmax, const float* __restrict__ normsum,
    const float* __restrict__ cnt, const float* __restrict__ hidden,
    float* __restrict__ out, int E, int Etot, int N, int selfRel,
    int r0, int r1) {
  int tid = blockIdx.x * 256 + threadIdx.x;
  int e = tid >> 3, h = tid & 7;
  if (e >= Etot) return;
  int s, d, r; float ewv;
  if (e < E) { s = el[3 * e]; d = el[3 * e + 1]; r = el[3 * e + 2]; ewv = ew[e]; }
  else       { s = d = e - E; r = selfRel; ewv = 1.0f; }
  if (r < r0 || r >= r1) return;
  float a = A[((size_t)r * N + s) * NH + h];
  float b = B[((size_t)r * N + d) * NH + h];
  float w = leaky(a + b);
  float m = decf(wmax[(size_t)d * NH + h]);
  float c  = cnt[d];
  float ns = normsum[(size_t)d * NH + h];
  float attp = expf(w - m) * ewv / (ns / c + EPSV);
  const float4* hv = (const float4*)(hidden + ((size_t)(r - r0) * N + s) * ODIM + h * 16);
  float* op = out + (size_t)d * ODIM + h * 16;
  #pragma unroll
  for (int j = 0; j < 4; ++j) {
    float4 v = hv[j];
    atomicAdd(op + j * 4 + 0, attp * v.x);
    atomicAdd(op + j * 4 + 1, attp * v.y);
    atomicAdd(op + j * 4 + 2, attp * v.z);
    atomicAdd(op + j * 4 + 3, attp * v.w);
  }
}

// ---------------------------------------------------------------------------
// out = relu(out / cnt)
// ---------------------------------------------------------------------------
__global__ __launch_bounds__(256) void k_fin(
    float* __restrict__ out, const float* __restrict__ cnt, int total) {
  int tid = blockIdx.x * 256 + threadIdx.x;
  if (tid >= total) return;
  int n = tid >> 7;
  float v = out[tid] / cnt[n];
  out[tid] = v > 0.f ? v : 0.f;
}

extern "C" void kernel_launch(void* const* d_in, const int* in_sizes, int n_in,
                              void* d_out, int out_size, void* d_ws, size_t ws_size,
                              hipStream_t stream) {
  const float* x     = (const float*)d_in[0];
  const int*   el    = (const int*)d_in[1];
  const float* ew    = (const float*)d_in[2];
  const float* W     = (const float*)d_in[3];
  const float* query = (const float*)d_in[4];
  const int N    = in_sizes[0] / IDIM;
  const int E    = in_sizes[1] / 3;
  const int Rp1  = in_sizes[3] / (ODIM * IDIM);
  const int Etot = E + N;
  const int selfRel = Rp1 - 1;
  float* out = (float*)d_out;

  // ---- workspace carve-up (ws_size-adaptive) ----
  auto align256 = [](size_t v) { return (v + 255) & ~(size_t)255; };
  char* ws = (char*)d_ws;
  size_t off = 0;
  const size_t ab_bytes   = align256((size_t)Rp1 * N * NH * 4);
  const size_t qw_bytes   = align256((size_t)Rp1 * NH * IDIM * 4);
  const size_t wmax_bytes = align256((size_t)N * NH * 4);
  const size_t cnt_bytes  = align256((size_t)N * 4);
  const size_t xb_bytes   = align256((size_t)N * IDIM * 2);
  const size_t wb_bytes   = align256((size_t)Rp1 * ODIM * IDIM * 2);
  const size_t per_rel    = (size_t)N * ODIM * 4;

  float*    A       = (float*)(ws + off);    off += ab_bytes;
  float*    B       = (float*)(ws + off);    off += ab_bytes;
  float*    qWe     = (float*)(ws + off);    off += qw_bytes;
  float*    qWo     = (float*)(ws + off);    off += qw_bytes;
  unsigned* wmax    = (unsigned*)(ws + off); off += wmax_bytes;
  float*    normsum = (float*)(ws + off);    off += wmax_bytes;
  float*    cnt     = (float*)(ws + off);    off += cnt_bytes;
  unsigned short* xhi = (unsigned short*)(ws + off); off += xb_bytes;
  unsigned short* xlo = (unsigned short*)(ws + off); off += xb_bytes;
  unsigned short* whi = (unsigned short*)(ws + off); off += wb_bytes;
  unsigned short* wlo = (unsigned short*)(ws + off); off += wb_bytes;
  float*    hidden  = (float*)(ws + off);    // chunk buffer, RC relations

  int RC = 1;
  if (ws_size > off + per_rel) {
    size_t fit = (ws_size - off) / per_rel;
    RC = (int)(fit < (size_t)Rp1 ? fit : (size_t)Rp1);
    if (RC < 1) RC = 1;
  }

  // ---- launches ----
  int x4 = N * IDIM / 4;
  k_cvt<<<(x4 + 255) / 256, 256, 0, stream>>>(x, (ushort4*)xhi, (ushort4*)xlo, x4);
  int w4 = Rp1 * ODIM * IDIM / 4;
  k_cvt<<<(w4 + 255) / 256, 256, 0, stream>>>(W, (ushort4*)whi, (ushort4*)wlo, w4);

  int qw_total = Rp1 * NH * IDIM;
  k_qw<<<(qw_total + 255) / 256, 256, 0, stream>>>(W, query, qWe, qWo, qw_total);
  k_AB<<<(N + 15) / 16, 256, 0, stream>>>(x, qWe, qWo, A, B, N, Rp1);
  k_init<<<(N * ODIM + 255) / 256, 256, 0, stream>>>(out, wmax, normsum, cnt, N);
  k_wmax<<<(Etot + 255) / 256, 256, 0, stream>>>(el, A, B, wmax, cnt, E, Etot, N, selfRel);
  k_norm<<<(Etot + 255) / 256, 256, 0, stream>>>(el, ew, A, B, wmax, normsum, E, Etot, N, selfRel);

  long long nsc = (long long)Etot * NH;
  int sc_blocks = (int)((nsc + 255) / 256);
  for (int r0 = 0; r0 < Rp1; r0 += RC) {
    int rc = (r0 + RC <= Rp1) ? RC : (Rp1 - r0);
    dim3 gh(GEMM_GX, rc);
    k_mfma_hidden<<<gh, 256, 0, stream>>>(xhi, xlo, whi, wlo, hidden, N, r0);
    k_scatter<<<sc_blocks, 256, 0, stream>>>(el, ew, A, B, wmax, normsum, cnt,
                                             hidden, out, E, Etot, N, selfRel,
                                             r0, r0 + rc);
  }
  k_fin<<<(N * ODIM + 255) / 256, 256, 0, stream>>>(out, cnt, N * ODIM);
}

// Round 8
// 2670.184 us; speedup vs baseline: 5.1231x; 5.1231x over previous
//
#include <hip/hip_runtime.h>

#define IDIM 128
#define ODIM 128
#define NH   8
#define DQH  32      // 2*ODIM/NH
#define EPSV 1e-10f
#define GEMM_GX 120

typedef __attribute__((ext_vector_type(8))) short bf16x8;
typedef __attribute__((ext_vector_type(4))) float f32x4;

__device__ __forceinline__ float leaky(float w) { return w > 0.f ? w : 0.2f * w; }

// order-preserving float <-> u32 encoding for atomicMax
__device__ __forceinline__ unsigned encf(float f) {
  unsigned b = __float_as_uint(f);
  return (b & 0x80000000u) ? ~b : (b | 0x80000000u);
}
__device__ __forceinline__ float decf(unsigned e) {
  unsigned b = (e & 0x80000000u) ? (e & 0x7fffffffu) : ~e;
  return __uint_as_float(b);
}

__device__ __forceinline__ unsigned short f2bf(float f) {  // RNE
  unsigned u = __float_as_uint(f);
  u = u + 0x7fffu + ((u >> 16) & 1u);
  return (unsigned short)(u >> 16);
}
__device__ __forceinline__ float bf2f(unsigned short h) {
  return __uint_as_float(((unsigned)h) << 16);
}

// ---------------------------------------------------------------------------
// split-bf16 conversion: hi = bf16(v), lo = bf16(v - hi)
// ---------------------------------------------------------------------------
__global__ __launch_bounds__(256) void k_cvt(
    const float* __restrict__ in, ushort4* __restrict__ hi,
    ushort4* __restrict__ lo, int total4) {
  int i = blockIdx.x * 256 + threadIdx.x;
  if (i >= total4) return;
  float4 v = ((const float4*)in)[i];
  ushort4 h, l;
  h.x = f2bf(v.x); l.x = f2bf(v.x - bf2f(h.x));
  h.y = f2bf(v.y); l.y = f2bf(v.y - bf2f(h.y));
  h.z = f2bf(v.z); l.z = f2bf(v.z - bf2f(h.z));
  h.w = f2bf(v.w); l.w = f2bf(v.w - bf2f(h.w));
  hi[i] = h; lo[i] = l;
}

// ---------------------------------------------------------------------------
// MFMA GEMM (3-term split-bf16): hidden[ry][n][o] = sum_d x[n][d]*W[r0+ry][o][d]
// ---------------------------------------------------------------------------
__global__ __launch_bounds__(256) void k_mfma_hidden(
    const unsigned short* __restrict__ xhi, const unsigned short* __restrict__ xlo,
    const unsigned short* __restrict__ whi, const unsigned short* __restrict__ wlo,
    float* __restrict__ hidden, int Nn, int r0) {
  const int ry = blockIdx.y;
  const int r  = r0 + ry;
  __shared__ unsigned short WL[2][4][8][64][8];  // 64 KB
  const int t = threadIdx.x;
  for (int idx = t; idx < 2 * 4 * 8 * 64; idx += 256) {
    int half = idx >> 11;
    int rem  = idx & 2047;
    int ks   = rem >> 9;
    int ot   = (rem >> 6) & 7;
    int ln   = rem & 63;
    int orow = ot * 16 + (ln & 15);
    int kcol = ks * 32 + (ln >> 4) * 8;
    const unsigned short* src =
        (half ? wlo : whi) + (size_t)r * ODIM * IDIM + orow * IDIM + kcol;
    *(ulonglong2*)(&WL[half][ks][ot][ln][0]) = *(const ulonglong2*)src;
  }
  __syncthreads();

  const int wave = t >> 6, lane = t & 63;
  const int lrow = lane & 15, lk8 = lane >> 4;

  for (int tile = blockIdx.x; tile * 64 < Nn; tile += GEMM_GX) {
    int n0 = tile * 64 + wave * 16;
    int nrow = n0 + lrow; if (nrow >= Nn) nrow = Nn - 1;
    const unsigned short* xh = xhi + (size_t)nrow * IDIM + lk8 * 8;
    const unsigned short* xl = xlo + (size_t)nrow * IDIM + lk8 * 8;

    f32x4 acc[8] = {};
    #pragma unroll
    for (int ks = 0; ks < 4; ++ks) {
      bf16x8 ah = *(const bf16x8*)(xh + ks * 32);
      bf16x8 al = *(const bf16x8*)(xl + ks * 32);
      #pragma unroll
      for (int ot = 0; ot < 8; ++ot) {
        bf16x8 bh = *(const bf16x8*)(&WL[0][ks][ot][lane][0]);
        bf16x8 bl = *(const bf16x8*)(&WL[1][ks][ot][lane][0]);
        acc[ot] = __builtin_amdgcn_mfma_f32_16x16x32_bf16(ah, bh, acc[ot], 0, 0, 0);
        acc[ot] = __builtin_amdgcn_mfma_f32_16x16x32_bf16(ah, bl, acc[ot], 0, 0, 0);
        acc[ot] = __builtin_amdgcn_mfma_f32_16x16x32_bf16(al, bh, acc[ot], 0, 0, 0);
      }
    }
    float* hbase = hidden + ((size_t)ry * Nn + n0) * ODIM;
    #pragma unroll
    for (int ot = 0; ot < 8; ++ot) {
      #pragma unroll
      for (int reg = 0; reg < 4; ++reg) {
        int nodeo = lk8 * 4 + reg;
        if (n0 + nodeo < Nn)
          hbase[(size_t)nodeo * ODIM + ot * 16 + lrow] = acc[ot][reg];
      }
    }
  }
}

// ---------------------------------------------------------------------------
// qWe/qWo: query-projected weights
// ---------------------------------------------------------------------------
__global__ __launch_bounds__(256) void k_qw(
    const float* __restrict__ W, const float* __restrict__ query,
    float* __restrict__ qWe, float* __restrict__ qWo, int total) {
  int idx = blockIdx.x * 256 + threadIdx.x;
  if (idx >= total) return;
  int d  = idx & 127;
  int rh = idx >> 7;
  int r = rh >> 3, h = rh & 7;
  const float* q  = query + (size_t)rh * DQH;
  const float* Wb = W + ((size_t)r * ODIM + h * 16) * IDIM + d;
  float se = 0.f, so = 0.f;
  #pragma unroll
  for (int j = 0; j < 16; ++j) {
    float wv = Wb[(size_t)j * IDIM];
    se += q[2 * j] * wv;
    so += q[2 * j + 1] * wv;
  }
  qWe[idx] = se;
  qWo[idx] = so;
}

// ---------------------------------------------------------------------------
// A[r][n][h] = qWe[r][h][:] . x[n][:] ;  B likewise with qWo
// ---------------------------------------------------------------------------
__global__ __launch_bounds__(256) void k_AB(
    const float* __restrict__ x, const float* __restrict__ qWe,
    const float* __restrict__ qWo, float* __restrict__ A, float* __restrict__ B,
    int N, int Rp1) {
  __shared__ float xs[16][132];
  const int n0 = blockIdx.x * 16;
  const int t = threadIdx.x;
  for (int i = t; i < 16 * 32; i += 256) {
    int node = i >> 5, c4 = i & 31;
    int n = n0 + node;
    float4 v = make_float4(0.f, 0.f, 0.f, 0.f);
    if (n < N) v = *(const float4*)(x + (size_t)n * IDIM + c4 * 4);
    *(float4*)(&xs[node][c4 * 4]) = v;
  }
  __syncthreads();
  const int node = t >> 4;
  const int lane = t & 15;
  const int n = n0 + node;
  if (n >= N) return;
  const float4* xr = (const float4*)(&xs[node][0]);
  const int nrh = Rp1 * NH;
  for (int rh = lane; rh < nrh; rh += 16) {
    const float4* qe = (const float4*)(qWe + (size_t)rh * IDIM);
    const float4* qo = (const float4*)(qWo + (size_t)rh * IDIM);
    float se0 = 0, se1 = 0, se2 = 0, se3 = 0;
    float so0 = 0, so1 = 0, so2 = 0, so3 = 0;
    #pragma unroll
    for (int d4 = 0; d4 < 32; ++d4) {
      float4 xv = xr[d4], ev = qe[d4], ov = qo[d4];
      se0 += ev.x * xv.x; se1 += ev.y * xv.y; se2 += ev.z * xv.z; se3 += ev.w * xv.w;
      so0 += ov.x * xv.x; so1 += ov.y * xv.y; so2 += ov.z * xv.z; so3 += ov.w * xv.w;
    }
    int r = rh >> 3, h = rh & 7;
    A[((size_t)r * N + n) * NH + h] = (se0 + se1) + (se2 + se3);
    B[((size_t)r * N + n) * NH + h] = (so0 + so1) + (so2 + so3);
  }
}

// ---------------------------------------------------------------------------
// zero everything (ws is poisoned 0xAA before each replay)
// ---------------------------------------------------------------------------
__global__ __launch_bounds__(256) void k_init(
    float* __restrict__ out, unsigned* __restrict__ wmax,
    float* __restrict__ normsum, float* __restrict__ cnt,
    int* __restrict__ deg, int* __restrict__ cursor, int N) {
  int tid = blockIdx.x * 256 + threadIdx.x;
  if (tid < N * ODIM) out[tid] = 0.f;
  if (tid < N * NH) { wmax[tid] = 0u; normsum[tid] = 0.f; }
  if (tid < N) { cnt[tid] = 0.f; deg[tid] = 0; cursor[tid] = 0; }
}

// ---------------------------------------------------------------------------
// CSR step 1: in-degree count (real edges only)
// ---------------------------------------------------------------------------
__global__ __launch_bounds__(256) void k_deg(
    const int* __restrict__ el, int* __restrict__ deg, int E) {
  int e = blockIdx.x * 256 + threadIdx.x;
  if (e >= E) return;
  atomicAdd(&deg[el[3 * e + 1]], 1);
}

// ---------------------------------------------------------------------------
// CSR step 2: exclusive prefix scan over deg -> off[0..N]  (single block)
// ---------------------------------------------------------------------------
__global__ __launch_bounds__(256) void k_scan(
    const int* __restrict__ deg, int* __restrict__ off, int N) {
  __shared__ int sums[256];
  __shared__ int pref[257];
  const int t = threadIdx.x;
  const int C = (N + 255) / 256;
  const int lo = t * C, hi = min(N, lo + C);
  int s = 0;
  for (int i = lo; i < hi; ++i) s += deg[i];
  sums[t] = s;
  __syncthreads();
  if (t == 0) {
    int run = 0;
    for (int i = 0; i < 256; ++i) { pref[i] = run; run += sums[i]; }
    pref[256] = run;
  }
  __syncthreads();
  int run = pref[t];
  for (int i = lo; i < hi; ++i) { off[i] = run; run += deg[i]; }
  if (lo < N && hi == N) off[N] = run;
}

// ---------------------------------------------------------------------------
// CSR step 3: fill slots; spacked = s | (r<<20)
// ---------------------------------------------------------------------------
__global__ __launch_bounds__(256) void k_fill(
    const int* __restrict__ el, const int* __restrict__ off,
    int* __restrict__ cursor, int* __restrict__ eidx,
    int* __restrict__ spacked, int E) {
  int e = blockIdx.x * 256 + threadIdx.x;
  if (e >= E) return;
  int s = el[3 * e], d = el[3 * e + 1], r = el[3 * e + 2];
  int slot = off[d] + atomicAdd(&cursor[d], 1);
  eidx[slot] = e;
  spacked[slot] = s | (r << 20);
}

// ---------------------------------------------------------------------------
// per edge: w[h] = leaky(A+B); wmax atomicMax; cnt += 1
// ---------------------------------------------------------------------------
__global__ __launch_bounds__(256) void k_wmax(
    const int* __restrict__ el, const float* __restrict__ A,
    const float* __restrict__ B, unsigned* __restrict__ wmax,
    float* __restrict__ cnt, int E, int Etot, int N, int selfRel) {
  int e = blockIdx.x * 256 + threadIdx.x;
  if (e >= Etot) return;
  int s, d, r;
  if (e < E) { s = el[3 * e]; d = el[3 * e + 1]; r = el[3 * e + 2]; }
  else       { s = d = e - E; r = selfRel; }
  const float4* Ap = (const float4*)(A + ((size_t)r * N + s) * NH);
  const float4* Bp = (const float4*)(B + ((size_t)r * N + d) * NH);
  float4 a0 = Ap[0], a1 = Ap[1], b0 = Bp[0], b1 = Bp[1];
  unsigned* wm = wmax + (size_t)d * NH;
  atomicMax(&wm[0], encf(leaky(a0.x + b0.x)));
  atomicMax(&wm[1], encf(leaky(a0.y + b0.y)));
  atomicMax(&wm[2], encf(leaky(a0.z + b0.z)));
  atomicMax(&wm[3], encf(leaky(a0.w + b0.w)));
  atomicMax(&wm[4], encf(leaky(a1.x + b1.x)));
  atomicMax(&wm[5], encf(leaky(a1.y + b1.y)));
  atomicMax(&wm[6], encf(leaky(a1.z + b1.z)));
  atomicMax(&wm[7], encf(leaky(a1.w + b1.w)));
  atomicAdd(&cnt[d], 1.0f);
}

// ---------------------------------------------------------------------------
// per edge: att[h] = exp(w - wmax)*ew ; normsum[d][h] += att[h]
// ---------------------------------------------------------------------------
__global__ __launch_bounds__(256) void k_norm(
    const int* __restrict__ el, const float* __restrict__ ew,
    const float* __restrict__ A, const float* __restrict__ B,
    const unsigned* __restrict__ wmax, float* __restrict__ normsum,
    int E, int Etot, int N, int selfRel) {
  int e = blockIdx.x * 256 + threadIdx.x;
  if (e >= Etot) return;
  int s, d, r; float ewv;
  if (e < E) { s = el[3 * e]; d = el[3 * e + 1]; r = el[3 * e + 2]; ewv = ew[e]; }
  else       { s = d = e - E; r = selfRel; ewv = 1.0f; }
  const float4* Ap = (const float4*)(A + ((size_t)r * N + s) * NH);
  const float4* Bp = (const float4*)(B + ((size_t)r * N + d) * NH);
  float4 a0 = Ap[0], a1 = Ap[1], b0 = Bp[0], b1 = Bp[1];
  const unsigned* wm = wmax + (size_t)d * NH;
  float* ns = normsum + (size_t)d * NH;
  float wv[8] = {a0.x + b0.x, a0.y + b0.y, a0.z + b0.z, a0.w + b0.w,
                 a1.x + b1.x, a1.y + b1.y, a1.z + b1.z, a1.w + b1.w};
  #pragma unroll
  for (int h = 0; h < 8; ++h) {
    float att = expf(leaky(wv[h]) - decf(wm[h])) * ewv;
    atomicAdd(&ns[h], att);
  }
}

// ---------------------------------------------------------------------------
// attw[slot][h] = fully normalized attention weight
// slots 0..E-1 are CSR order; slot E+d is node d's self-loop.
// ---------------------------------------------------------------------------
__global__ __launch_bounds__(256) void k_attpre(
    const int* __restrict__ el, const float* __restrict__ ew,
    const int* __restrict__ eidx, const float* __restrict__ A,
    const float* __restrict__ B, const unsigned* __restrict__ wmax,
    const float* __restrict__ normsum, const float* __restrict__ cnt,
    float* __restrict__ attw, int E, int Etot, int N, int selfRel) {
  int tid = blockIdx.x * 256 + threadIdx.x;
  int slot = tid >> 3, h = tid & 7;
  if (slot >= Etot) return;
  int s, d, r; float ewv;
  if (slot < E) {
    int e = eidx[slot];
    s = el[3 * e]; d = el[3 * e + 1]; r = el[3 * e + 2]; ewv = ew[e];
  } else {
    s = d = slot - E; r = selfRel; ewv = 1.0f;
  }
  float a = A[((size_t)r * N + s) * NH + h];
  float b = B[((size_t)r * N + d) * NH + h];
  float w = leaky(a + b);
  float m = decf(wmax[(size_t)d * NH + h]);
  float c  = cnt[d];
  float ns = normsum[(size_t)d * NH + h];
  attw[(size_t)slot * NH + h] = expf(w - m) * ewv / (ns / c + EPSV);
}

// ---------------------------------------------------------------------------
// gather: one block (4 waves) per dst node. No atomics.
// out[d] += sum over in-slots with r in [r0,r1) of attw[slot][h] * hidden[r][s]
// ---------------------------------------------------------------------------
__global__ __launch_bounds__(256) void k_gather(
    const int* __restrict__ off, const int* __restrict__ spacked,
    const float* __restrict__ attw, const float* __restrict__ hidden,
    float* __restrict__ out, int E, int N, int selfRel, int r0, int r1) {
  const int d = blockIdx.x;
  const int t = threadIdx.x;
  const int wave = t >> 6, lane = t & 63;
  const int base = off[d];
  const int degd = off[d + 1] - base;
  const int hasSelf = (selfRel >= r0 && selfRel < r1) ? 1 : 0;
  const int nslots = degd + hasSelf;
  const int h = lane >> 3;  // head for both float2 components (o = lane*2, lane*2+1)

  float ax = 0.f, ay = 0.f;
  for (int j = wave; j < nslots; j += 4) {
    int s, r; size_t aslot;
    if (j < degd) {
      int sp = spacked[base + j];
      s = sp & 0xFFFFF; r = sp >> 20;
      if (r < r0 || r >= r1) continue;
      aslot = (size_t)(base + j);
    } else {
      s = d; r = selfRel;
      aslot = (size_t)E + d;
    }
    float av = attw[aslot * NH + h];
    const float2 hv = *(const float2*)(hidden + (((size_t)(r - r0) * N + s) << 7) + lane * 2);
    ax += av * hv.x;
    ay += av * hv.y;
  }

  __shared__ float part[4][128];
  part[wave][lane * 2]     = ax;
  part[wave][lane * 2 + 1] = ay;
  __syncthreads();
  if (t < 128) {
    float s = part[0][t] + part[1][t] + part[2][t] + part[3][t];
    out[((size_t)d << 7) + t] += s;
  }
}

// ---------------------------------------------------------------------------
// out = relu(out / cnt)
// ---------------------------------------------------------------------------
__global__ __launch_bounds__(256) void k_fin(
    float* __restrict__ out, const float* __restrict__ cnt, int total) {
  int tid = blockIdx.x * 256 + threadIdx.x;
  if (tid >= total) return;
  int n = tid >> 7;
  float v = out[tid] / cnt[n];
  out[tid] = v > 0.f ? v : 0.f;
}

extern "C" void kernel_launch(void* const* d_in, const int* in_sizes, int n_in,
                              void* d_out, int out_size, void* d_ws, size_t ws_size,
                              hipStream_t stream) {
  const float* x     = (const float*)d_in[0];
  const int*   el    = (const int*)d_in[1];
  const float* ew    = (const float*)d_in[2];
  const float* W     = (const float*)d_in[3];
  const float* query = (const float*)d_in[4];
  const int N    = in_sizes[0] / IDIM;
  const int E    = in_sizes[1] / 3;
  const int Rp1  = in_sizes[3] / (ODIM * IDIM);
  const int Etot = E + N;
  const int selfRel = Rp1 - 1;
  float* out = (float*)d_out;

  // ---- workspace carve-up (ws_size-adaptive) ----
  auto align256 = [](size_t v) { return (v + 255) & ~(size_t)255; };
  char* ws = (char*)d_ws;
  size_t off_b = 0;
  const size_t ab_bytes   = align256((size_t)Rp1 * N * NH * 4);
  const size_t qw_bytes   = align256((size_t)Rp1 * NH * IDIM * 4);
  const size_t wmax_bytes = align256((size_t)N * NH * 4);
  const size_t cnt_bytes  = align256((size_t)N * 4);
  const size_t xb_bytes   = align256((size_t)N * IDIM * 2);
  const size_t wb_bytes   = align256((size_t)Rp1 * ODIM * IDIM * 2);
  const size_t int_bytes  = align256((size_t)(N + 1) * 4);
  const size_t eidx_bytes = align256((size_t)E * 4);
  const size_t attw_bytes = align256((size_t)Etot * NH * 4);
  const size_t per_rel    = (size_t)N * ODIM * 4;

  float*    A       = (float*)(ws + off_b);    off_b += ab_bytes;
  float*    B       = (float*)(ws + off_b);    off_b += ab_bytes;
  float*    qWe     = (float*)(ws + off_b);    off_b += qw_bytes;
  float*    qWo     = (float*)(ws + off_b);    off_b += qw_bytes;
  unsigned* wmax    = (unsigned*)(ws + off_b); off_b += wmax_bytes;
  float*    normsum = (float*)(ws + off_b);    off_b += wmax_bytes;
  float*    cnt     = (float*)(ws + off_b);    off_b += cnt_bytes;
  unsigned short* xhi = (unsigned short*)(ws + off_b); off_b += xb_bytes;
  unsigned short* xlo = (unsigned short*)(ws + off_b); off_b += xb_bytes;
  unsigned short* whi = (unsigned short*)(ws + off_b); off_b += wb_bytes;
  unsigned short* wlo = (unsigned short*)(ws + off_b); off_b += wb_bytes;
  int*      deg     = (int*)(ws + off_b);      off_b += int_bytes;
  int*      csroff  = (int*)(ws + off_b);      off_b += int_bytes;
  int*      cursor  = (int*)(ws + off_b);      off_b += int_bytes;
  int*      eidx    = (int*)(ws + off_b);      off_b += eidx_bytes;
  int*      spacked = (int*)(ws + off_b);      off_b += eidx_bytes;
  float*    attw    = (float*)(ws + off_b);    off_b += attw_bytes;
  float*    hidden  = (float*)(ws + off_b);    // chunk buffer, RC relations

  int RC = 1;
  if (ws_size > off_b + per_rel) {
    size_t fit = (ws_size - off_b) / per_rel;
    RC = (int)(fit < (size_t)Rp1 ? fit : (size_t)Rp1);
    if (RC < 1) RC = 1;
  }

  // ---- launches ----
  k_init<<<(N * ODIM + 255) / 256, 256, 0, stream>>>(out, wmax, normsum, cnt,
                                                     deg, cursor, N);
  k_deg<<<(E + 255) / 256, 256, 0, stream>>>(el, deg, E);
  k_scan<<<1, 256, 0, stream>>>(deg, csroff, N);
  k_fill<<<(E + 255) / 256, 256, 0, stream>>>(el, csroff, cursor, eidx, spacked, E);

  int x4 = N * IDIM / 4;
  k_cvt<<<(x4 + 255) / 256, 256, 0, stream>>>(x, (ushort4*)xhi, (ushort4*)xlo, x4);
  int w4 = Rp1 * ODIM * IDIM / 4;
  k_cvt<<<(w4 + 255) / 256, 256, 0, stream>>>(W, (ushort4*)whi, (ushort4*)wlo, w4);

  int qw_total = Rp1 * NH * IDIM;
  k_qw<<<(qw_total + 255) / 256, 256, 0, stream>>>(W, query, qWe, qWo, qw_total);
  k_AB<<<(N + 15) / 16, 256, 0, stream>>>(x, qWe, qWo, A, B, N, Rp1);
  k_wmax<<<(Etot + 255) / 256, 256, 0, stream>>>(el, A, B, wmax, cnt, E, Etot, N, selfRel);
  k_norm<<<(Etot + 255) / 256, 256, 0, stream>>>(el, ew, A, B, wmax, normsum, E, Etot, N, selfRel);

  long long natt = (long long)Etot * NH;
  k_attpre<<<(int)((natt + 255) / 256), 256, 0, stream>>>(el, ew, eidx, A, B, wmax,
                                                          normsum, cnt, attw,
                                                          E, Etot, N, selfRel);

  for (int r0 = 0; r0 < Rp1; r0 += RC) {
    int rc = (r0 + RC <= Rp1) ? RC : (Rp1 - r0);
    dim3 gh(GEMM_GX, rc);
    k_mfma_hidden<<<gh, 256, 0, stream>>>(xhi, xlo, whi, wlo, hidden, N, r0);
    k_gather<<<N, 256, 0, stream>>>(csroff, spacked, attw, hidden, out,
                                    E, N, selfRel, r0, r0 + rc);
  }
  k_fin<<<(N * ODIM + 255) / 256, 256, 0, stream>>>(out, cnt, N * ODIM);
}

// Round 9
// 1317.060 us; speedup vs baseline: 10.3866x; 2.0274x over previous
//
#include <hip/hip_runtime.h>

#define IDIM 128
#define ODIM 128
#define NH   8
#define DQH  32      // 2*ODIM/NH
#define EPSV 1e-10f
#define GEMM_GX 120

typedef __attribute__((ext_vector_type(8))) short bf16x8;
typedef __attribute__((ext_vector_type(4))) float f32x4;

__device__ __forceinline__ float leaky(float w) { return w > 0.f ? w : 0.2f * w; }

__device__ __forceinline__ unsigned short f2bf(float f) {  // RNE
  unsigned u = __float_as_uint(f);
  u = u + 0x7fffu + ((u >> 16) & 1u);
  return (unsigned short)(u >> 16);
}
__device__ __forceinline__ float bf2f(unsigned short h) {
  return __uint_as_float(((unsigned)h) << 16);
}

// ---------------------------------------------------------------------------
// split-bf16 conversion: hi = bf16(v), lo = bf16(v - hi)
// ---------------------------------------------------------------------------
__global__ __launch_bounds__(256) void k_cvt(
    const float* __restrict__ in, ushort4* __restrict__ hi,
    ushort4* __restrict__ lo, int total4) {
  int i = blockIdx.x * 256 + threadIdx.x;
  if (i >= total4) return;
  float4 v = ((const float4*)in)[i];
  ushort4 h, l;
  h.x = f2bf(v.x); l.x = f2bf(v.x - bf2f(h.x));
  h.y = f2bf(v.y); l.y = f2bf(v.y - bf2f(h.y));
  h.z = f2bf(v.z); l.z = f2bf(v.z - bf2f(h.z));
  h.w = f2bf(v.w); l.w = f2bf(v.w - bf2f(h.w));
  hi[i] = h; lo[i] = l;
}

// ---------------------------------------------------------------------------
// MFMA GEMM (3-term split-bf16): hidden[ry][n][o] = sum_d x[n][d]*W[r0+ry][o][d]
// ---------------------------------------------------------------------------
__global__ __launch_bounds__(256) void k_mfma_hidden(
    const unsigned short* __restrict__ xhi, const unsigned short* __restrict__ xlo,
    const unsigned short* __restrict__ whi, const unsigned short* __restrict__ wlo,
    float* __restrict__ hidden, int Nn, int r0) {
  const int ry = blockIdx.y;
  const int r  = r0 + ry;
  __shared__ unsigned short WL[2][4][8][64][8];  // 64 KB
  const int t = threadIdx.x;
  for (int idx = t; idx < 2 * 4 * 8 * 64; idx += 256) {
    int half = idx >> 11;
    int rem  = idx & 2047;
    int ks   = rem >> 9;
    int ot   = (rem >> 6) & 7;
    int ln   = rem & 63;
    int orow = ot * 16 + (ln & 15);
    int kcol = ks * 32 + (ln >> 4) * 8;
    const unsigned short* src =
        (half ? wlo : whi) + (size_t)r * ODIM * IDIM + orow * IDIM + kcol;
    *(ulonglong2*)(&WL[half][ks][ot][ln][0]) = *(const ulonglong2*)src;
  }
  __syncthreads();

  const int wave = t >> 6, lane = t & 63;
  const int lrow = lane & 15, lk8 = lane >> 4;

  for (int tile = blockIdx.x; tile * 64 < Nn; tile += GEMM_GX) {
    int n0 = tile * 64 + wave * 16;
    int nrow = n0 + lrow; if (nrow >= Nn) nrow = Nn - 1;
    const unsigned short* xh = xhi + (size_t)nrow * IDIM + lk8 * 8;
    const unsigned short* xl = xlo + (size_t)nrow * IDIM + lk8 * 8;

    f32x4 acc[8] = {};
    #pragma unroll
    for (int ks = 0; ks < 4; ++ks) {
      bf16x8 ah = *(const bf16x8*)(xh + ks * 32);
      bf16x8 al = *(const bf16x8*)(xl + ks * 32);
      #pragma unroll
      for (int ot = 0; ot < 8; ++ot) {
        bf16x8 bh = *(const bf16x8*)(&WL[0][ks][ot][lane][0]);
        bf16x8 bl = *(const bf16x8*)(&WL[1][ks][ot][lane][0]);
        acc[ot] = __builtin_amdgcn_mfma_f32_16x16x32_bf16(ah, bh, acc[ot], 0, 0, 0);
        acc[ot] = __builtin_amdgcn_mfma_f32_16x16x32_bf16(ah, bl, acc[ot], 0, 0, 0);
        acc[ot] = __builtin_amdgcn_mfma_f32_16x16x32_bf16(al, bh, acc[ot], 0, 0, 0);
      }
    }
    float* hbase = hidden + ((size_t)ry * Nn + n0) * ODIM;
    #pragma unroll
    for (int ot = 0; ot < 8; ++ot) {
      #pragma unroll
      for (int reg = 0; reg < 4; ++reg) {
        int nodeo = lk8 * 4 + reg;
        if (n0 + nodeo < Nn)
          hbase[(size_t)nodeo * ODIM + ot * 16 + lrow] = acc[ot][reg];
      }
    }
  }
}

// ---------------------------------------------------------------------------
// qWe/qWo: query-projected weights
// ---------------------------------------------------------------------------
__global__ __launch_bounds__(256) void k_qw(
    const float* __restrict__ W, const float* __restrict__ query,
    float* __restrict__ qWe, float* __restrict__ qWo, int total) {
  int idx = blockIdx.x * 256 + threadIdx.x;
  if (idx >= total) return;
  int d  = idx & 127;
  int rh = idx >> 7;
  int r = rh >> 3, h = rh & 7;
  const float* q  = query + (size_t)rh * DQH;
  const float* Wb = W + ((size_t)r * ODIM + h * 16) * IDIM + d;
  float se = 0.f, so = 0.f;
  #pragma unroll
  for (int j = 0; j < 16; ++j) {
    float wv = Wb[(size_t)j * IDIM];
    se += q[2 * j] * wv;
    so += q[2 * j + 1] * wv;
  }
  qWe[idx] = se;
  qWo[idx] = so;
}

// ---------------------------------------------------------------------------
// A[r][n][h] = qWe[r][h][:] . x[n][:] ;  B likewise with qWo
// ---------------------------------------------------------------------------
__global__ __launch_bounds__(256) void k_AB(
    const float* __restrict__ x, const float* __restrict__ qWe,
    const float* __restrict__ qWo, float* __restrict__ A, float* __restrict__ B,
    int N, int Rp1) {
  __shared__ float xs[16][132];
  const int n0 = blockIdx.x * 16;
  const int t = threadIdx.x;
  for (int i = t; i < 16 * 32; i += 256) {
    int node = i >> 5, c4 = i & 31;
    int n = n0 + node;
    float4 v = make_float4(0.f, 0.f, 0.f, 0.f);
    if (n < N) v = *(const float4*)(x + (size_t)n * IDIM + c4 * 4);
    *(float4*)(&xs[node][c4 * 4]) = v;
  }
  __syncthreads();
  const int node = t >> 4;
  const int lane = t & 15;
  const int n = n0 + node;
  if (n >= N) return;
  const float4* xr = (const float4*)(&xs[node][0]);
  const int nrh = Rp1 * NH;
  for (int rh = lane; rh < nrh; rh += 16) {
    const float4* qe = (const float4*)(qWe + (size_t)rh * IDIM);
    const float4* qo = (const float4*)(qWo + (size_t)rh * IDIM);
    float se0 = 0, se1 = 0, se2 = 0, se3 = 0;
    float so0 = 0, so1 = 0, so2 = 0, so3 = 0;
    #pragma unroll
    for (int d4 = 0; d4 < 32; ++d4) {
      float4 xv = xr[d4], ev = qe[d4], ov = qo[d4];
      se0 += ev.x * xv.x; se1 += ev.y * xv.y; se2 += ev.z * xv.z; se3 += ev.w * xv.w;
      so0 += ov.x * xv.x; so1 += ov.y * xv.y; so2 += ov.z * xv.z; so3 += ov.w * xv.w;
    }
    int r = rh >> 3, h = rh & 7;
    A[((size_t)r * N + n) * NH + h] = (se0 + se1) + (se2 + se3);
    B[((size_t)r * N + n) * NH + h] = (so0 + so1) + (so2 + so3);
  }
}

// ---------------------------------------------------------------------------
// zero out / deg / cursor (ws is poisoned 0xAA before each replay)
// ---------------------------------------------------------------------------
__global__ __launch_bounds__(256) void k_init(
    float* __restrict__ out, int* __restrict__ deg, int* __restrict__ cursor,
    int N) {
  int tid = blockIdx.x * 256 + threadIdx.x;
  if (tid < N * ODIM) out[tid] = 0.f;
  if (tid < N) { deg[tid] = 0; cursor[tid] = 0; }
}

// ---------------------------------------------------------------------------
// CSR step 1: in-degree count (real edges only)
// ---------------------------------------------------------------------------
__global__ __launch_bounds__(256) void k_deg(
    const int* __restrict__ el, int* __restrict__ deg, int E) {
  int e = blockIdx.x * 256 + threadIdx.x;
  if (e >= E) return;
  atomicAdd(&deg[el[3 * e + 1]], 1);
}

// ---------------------------------------------------------------------------
// CSR step 2: exclusive prefix scan over deg -> off[0..N]  (single block)
// ---------------------------------------------------------------------------
__global__ __launch_bounds__(256) void k_scan(
    const int* __restrict__ deg, int* __restrict__ off, int N) {
  __shared__ int sums[256];
  __shared__ int pref[257];
  const int t = threadIdx.x;
  const int C = (N + 255) / 256;
  const int lo = t * C, hi = min(N, lo + C);
  int s = 0;
  for (int i = lo; i < hi; ++i) s += deg[i];
  sums[t] = s;
  __syncthreads();
  if (t == 0) {
    int run = 0;
    for (int i = 0; i < 256; ++i) { pref[i] = run; run += sums[i]; }
    pref[256] = run;
  }
  __syncthreads();
  int run = pref[t];
  for (int i = lo; i < hi; ++i) { off[i] = run; run += deg[i]; }
  if (lo < N && hi == N) off[N] = run;
}

// ---------------------------------------------------------------------------
// CSR step 3: fill slots; spacked = s | (r<<20); ewp[slot] = edge weight
// ---------------------------------------------------------------------------
__global__ __launch_bounds__(256) void k_fill(
    const int* __restrict__ el, const float* __restrict__ ew,
    const int* __restrict__ off, int* __restrict__ cursor,
    int* __restrict__ spacked, float* __restrict__ ewp, int E) {
  int e = blockIdx.x * 256 + threadIdx.x;
  if (e >= E) return;
  int s = el[3 * e], d = el[3 * e + 1], r = el[3 * e + 2];
  int slot = off[d] + atomicAdd(&cursor[d], 1);
  spacked[slot] = s | (r << 20);
  ewp[slot] = ew[e];
}

// ---------------------------------------------------------------------------
// segment max + sum + attw, atomic-free. One wave per dst (4 dst/block).
// lane = jg*8 + h (jg = slot group 0..7, h = head). Self-loop = slot E+d.
// attw[slot][h] = exp(w - m)*ew (un-normalized); scale[d][h] = 1/(sum/cnt+EPS)
// ---------------------------------------------------------------------------
__global__ __launch_bounds__(256) void k_seg(
    const int* __restrict__ off, const int* __restrict__ spacked,
    const float* __restrict__ ewp, const float* __restrict__ A,
    const float* __restrict__ B, float* __restrict__ attw,
    float* __restrict__ scale, int E, int N, int selfRel) {
  const int d = blockIdx.x * 4 + (threadIdx.x >> 6);
  if (d >= N) return;
  const int lane = threadIdx.x & 63;
  const int jg = lane >> 3, h = lane & 7;
  const int base = off[d];
  const int degd = off[d + 1] - base;
  const int nslots = degd + 1;           // + self-loop

  // pass 1: max of leaky(A[r][s][h] + B[r][d][h])
  float m = -3.4e38f;
  for (int j = jg; j < nslots; j += 8) {
    int s, r;
    if (j < degd) { int sp = spacked[base + j]; s = sp & 0xFFFFF; r = sp >> 20; }
    else          { s = d; r = selfRel; }
    float w = leaky(A[((size_t)r * N + s) * NH + h] + B[((size_t)r * N + d) * NH + h]);
    m = fmaxf(m, w);
  }
  m = fmaxf(m, __shfl_xor(m, 8));
  m = fmaxf(m, __shfl_xor(m, 16));
  m = fmaxf(m, __shfl_xor(m, 32));

  // pass 2: attw = exp(w - m)*ew ; sum
  float sum = 0.f;
  for (int j = jg; j < nslots; j += 8) {
    int s, r; float ewv; size_t aslot;
    if (j < degd) {
      int sp = spacked[base + j]; s = sp & 0xFFFFF; r = sp >> 20;
      ewv = ewp[base + j]; aslot = (size_t)(base + j);
    } else {
      s = d; r = selfRel; ewv = 1.0f; aslot = (size_t)E + d;
    }
    float w = leaky(A[((size_t)r * N + s) * NH + h] + B[((size_t)r * N + d) * NH + h]);
    float att = expf(w - m) * ewv;
    attw[aslot * NH + h] = att;
    sum += att;
  }
  sum += __shfl_xor(sum, 8);
  sum += __shfl_xor(sum, 16);
  sum += __shfl_xor(sum, 32);

  if (jg == 0)
    scale[(size_t)d * NH + h] = 1.0f / (sum / (float)nslots + EPSV);
}

// ---------------------------------------------------------------------------
// gather: one block (4 waves) per dst node. No atomics.
// out[d] += sum over in-slots with r in [r0,r1) of attw*scale * hidden[r][s]
// ---------------------------------------------------------------------------
__global__ __launch_bounds__(256) void k_gather(
    const int* __restrict__ off, const int* __restrict__ spacked,
    const float* __restrict__ attw, const float* __restrict__ scale,
    const float* __restrict__ hidden, float* __restrict__ out,
    int E, int N, int selfRel, int r0, int r1) {
  const int d = blockIdx.x;
  const int t = threadIdx.x;
  const int wave = t >> 6, lane = t & 63;
  const int base = off[d];
  const int degd = off[d + 1] - base;
  const int hasSelf = (selfRel >= r0 && selfRel < r1) ? 1 : 0;
  const int nslots = degd + hasSelf;
  const int h = lane >> 3;  // head for both float2 components (o = lane*2, +1)
  const float sc = scale[(size_t)d * NH + h];

  float ax = 0.f, ay = 0.f;
  for (int j = wave; j < nslots; j += 4) {
    int s, r; size_t aslot;
    if (j < degd) {
      int sp = spacked[base + j];
      s = sp & 0xFFFFF; r = sp >> 20;
      if (r < r0 || r >= r1) continue;
      aslot = (size_t)(base + j);
    } else {
      s = d; r = selfRel;
      aslot = (size_t)E + d;
    }
    float av = attw[aslot * NH + h] * sc;
    const float2 hv = *(const float2*)(hidden + (((size_t)(r - r0) * N + s) << 7) + lane * 2);
    ax += av * hv.x;
    ay += av * hv.y;
  }

  __shared__ float part[4][128];
  part[wave][lane * 2]     = ax;
  part[wave][lane * 2 + 1] = ay;
  __syncthreads();
  if (t < 128) {
    float s = part[0][t] + part[1][t] + part[2][t] + part[3][t];
    out[((size_t)d << 7) + t] += s;
  }
}

// ---------------------------------------------------------------------------
// out = relu(out / cnt), cnt = deg+1 from CSR offsets
// ---------------------------------------------------------------------------
__global__ __launch_bounds__(256) void k_fin(
    float* __restrict__ out, const int* __restrict__ off, int total) {
  int tid = blockIdx.x * 256 + threadIdx.x;
  if (tid >= total) return;
  int n = tid >> 7;
  float c = (float)(off[n + 1] - off[n] + 1);
  float v = out[tid] / c;
  out[tid] = v > 0.f ? v : 0.f;
}

extern "C" void kernel_launch(void* const* d_in, const int* in_sizes, int n_in,
                              void* d_out, int out_size, void* d_ws, size_t ws_size,
                              hipStream_t stream) {
  const float* x     = (const float*)d_in[0];
  const int*   el    = (const int*)d_in[1];
  const float* ew    = (const float*)d_in[2];
  const float* W     = (const float*)d_in[3];
  const float* query = (const float*)d_in[4];
  const int N    = in_sizes[0] / IDIM;
  const int E    = in_sizes[1] / 3;
  const int Rp1  = in_sizes[3] / (ODIM * IDIM);
  const int Etot = E + N;
  const int selfRel = Rp1 - 1;
  float* out = (float*)d_out;

  // ---- workspace carve-up (ws_size-adaptive) ----
  auto align256 = [](size_t v) { return (v + 255) & ~(size_t)255; };
  char* ws = (char*)d_ws;
  size_t off_b = 0;
  const size_t ab_bytes    = align256((size_t)Rp1 * N * NH * 4);
  const size_t qw_bytes    = align256((size_t)Rp1 * NH * IDIM * 4);
  const size_t xb_bytes    = align256((size_t)N * IDIM * 2);
  const size_t wb_bytes    = align256((size_t)Rp1 * ODIM * IDIM * 2);
  const size_t int_bytes   = align256((size_t)(N + 1) * 4);
  const size_t slot_bytes  = align256((size_t)E * 4);
  const size_t attw_bytes  = align256((size_t)Etot * NH * 4);
  const size_t scale_bytes = align256((size_t)N * NH * 4);
  const size_t per_rel     = (size_t)N * ODIM * 4;

  float*    A       = (float*)(ws + off_b);    off_b += ab_bytes;
  float*    B       = (float*)(ws + off_b);    off_b += ab_bytes;
  float*    qWe     = (float*)(ws + off_b);    off_b += qw_bytes;
  float*    qWo     = (float*)(ws + off_b);    off_b += qw_bytes;
  unsigned short* xhi = (unsigned short*)(ws + off_b); off_b += xb_bytes;
  unsigned short* xlo = (unsigned short*)(ws + off_b); off_b += xb_bytes;
  unsigned short* whi = (unsigned short*)(ws + off_b); off_b += wb_bytes;
  unsigned short* wlo = (unsigned short*)(ws + off_b); off_b += wb_bytes;
  int*      deg     = (int*)(ws + off_b);      off_b += int_bytes;
  int*      csroff  = (int*)(ws + off_b);      off_b += int_bytes;
  int*      cursor  = (int*)(ws + off_b);      off_b += int_bytes;
  int*      spacked = (int*)(ws + off_b);      off_b += slot_bytes;
  float*    ewp     = (float*)(ws + off_b);    off_b += slot_bytes;
  float*    attw    = (float*)(ws + off_b);    off_b += attw_bytes;
  float*    scale   = (float*)(ws + off_b);    off_b += scale_bytes;
  float*    hidden  = (float*)(ws + off_b);    // chunk buffer, RC relations

  int RC = 1;
  if (ws_size > off_b + per_rel) {
    size_t fit = (ws_size - off_b) / per_rel;
    RC = (int)(fit < (size_t)Rp1 ? fit : (size_t)Rp1);
    if (RC < 1) RC = 1;
  }

  // ---- launches ----
  k_init<<<(N * ODIM + 255) / 256, 256, 0, stream>>>(out, deg, cursor, N);
  k_deg<<<(E + 255) / 256, 256, 0, stream>>>(el, deg, E);
  k_scan<<<1, 256, 0, stream>>>(deg, csroff, N);
  k_fill<<<(E + 255) / 256, 256, 0, stream>>>(el, ew, csroff, cursor,
                                              spacked, ewp, E);

  int x4 = N * IDIM / 4;
  k_cvt<<<(x4 + 255) / 256, 256, 0, stream>>>(x, (ushort4*)xhi, (ushort4*)xlo, x4);
  int w4 = Rp1 * ODIM * IDIM / 4;
  k_cvt<<<(w4 + 255) / 256, 256, 0, stream>>>(W, (ushort4*)whi, (ushort4*)wlo, w4);

  int qw_total = Rp1 * NH * IDIM;
  k_qw<<<(qw_total + 255) / 256, 256, 0, stream>>>(W, query, qWe, qWo, qw_total);
  k_AB<<<(N + 15) / 16, 256, 0, stream>>>(x, qWe, qWo, A, B, N, Rp1);

  k_seg<<<(N + 3) / 4, 256, 0, stream>>>(csroff, spacked, ewp, A, B, attw, scale,
                                         E, N, selfRel);

  for (int r0 = 0; r0 < Rp1; r0 += RC) {
    int rc = (r0 + RC <= Rp1) ? RC : (Rp1 - r0);
    dim3 gh(GEMM_GX, rc);
    k_mfma_hidden<<<gh, 256, 0, stream>>>(xhi, xlo, whi, wlo, hidden, N, r0);
    k_gather<<<N, 256, 0, stream>>>(csroff, spacked, attw, scale, hidden, out,
                                    E, N, selfRel, r0, r0 + rc);
  }
  k_fin<<<(N * ODIM + 255) / 256, 256, 0, stream>>>(out, csroff, N * ODIM);
}

// Round 10
// 916.080 us; speedup vs baseline: 14.9329x; 1.4377x over previous
//
#include <hip/hip_runtime.h>

#define IDIM 128
#define ODIM 128
#define NH   8
#define DQH  32      // 2*ODIM/NH
#define EPSV 1e-10f
#define GEMM_GX 120

typedef __attribute__((ext_vector_type(8))) short bf16x8;
typedef __attribute__((ext_vector_type(4))) float f32x4;

__device__ __forceinline__ float leaky(float w) { return w > 0.f ? w : 0.2f * w; }

__device__ __forceinline__ unsigned short f2bf(float f) {  // RNE
  unsigned u = __float_as_uint(f);
  u = u + 0x7fffu + ((u >> 16) & 1u);
  return (unsigned short)(u >> 16);
}
__device__ __forceinline__ float bf2f(unsigned short h) {
  return __uint_as_float(((unsigned)h) << 16);
}

// ---------------------------------------------------------------------------
// split-bf16 conversion: hi = bf16(v), lo = bf16(v - hi)
// ---------------------------------------------------------------------------
__global__ __launch_bounds__(256) void k_cvt(
    const float* __restrict__ in, ushort4* __restrict__ hi,
    ushort4* __restrict__ lo, int total4) {
  int i = blockIdx.x * 256 + threadIdx.x;
  if (i >= total4) return;
  float4 v = ((const float4*)in)[i];
  ushort4 h, l;
  h.x = f2bf(v.x); l.x = f2bf(v.x - bf2f(h.x));
  h.y = f2bf(v.y); l.y = f2bf(v.y - bf2f(h.y));
  h.z = f2bf(v.z); l.z = f2bf(v.z - bf2f(h.z));
  h.w = f2bf(v.w); l.w = f2bf(v.w - bf2f(h.w));
  hi[i] = h; lo[i] = l;
}

// ---------------------------------------------------------------------------
// MFMA GEMM (3-term split-bf16): hidden[ry][n][o] = sum_d x[n][d]*W[r0+ry][o][d]
// ---------------------------------------------------------------------------
__global__ __launch_bounds__(256) void k_mfma_hidden(
    const unsigned short* __restrict__ xhi, const unsigned short* __restrict__ xlo,
    const unsigned short* __restrict__ whi, const unsigned short* __restrict__ wlo,
    float* __restrict__ hidden, int Nn, int r0) {
  const int ry = blockIdx.y;
  const int r  = r0 + ry;
  __shared__ unsigned short WL[2][4][8][64][8];  // 64 KB
  const int t = threadIdx.x;
  for (int idx = t; idx < 2 * 4 * 8 * 64; idx += 256) {
    int half = idx >> 11;
    int rem  = idx & 2047;
    int ks   = rem >> 9;
    int ot   = (rem >> 6) & 7;
    int ln   = rem & 63;
    int orow = ot * 16 + (ln & 15);
    int kcol = ks * 32 + (ln >> 4) * 8;
    const unsigned short* src =
        (half ? wlo : whi) + (size_t)r * ODIM * IDIM + orow * IDIM + kcol;
    *(ulonglong2*)(&WL[half][ks][ot][ln][0]) = *(const ulonglong2*)src;
  }
  __syncthreads();

  const int wave = t >> 6, lane = t & 63;
  const int lrow = lane & 15, lk8 = lane >> 4;

  for (int tile = blockIdx.x; tile * 64 < Nn; tile += GEMM_GX) {
    int n0 = tile * 64 + wave * 16;
    int nrow = n0 + lrow; if (nrow >= Nn) nrow = Nn - 1;
    const unsigned short* xh = xhi + (size_t)nrow * IDIM + lk8 * 8;
    const unsigned short* xl = xlo + (size_t)nrow * IDIM + lk8 * 8;

    f32x4 acc[8] = {};
    #pragma unroll
    for (int ks = 0; ks < 4; ++ks) {
      bf16x8 ah = *(const bf16x8*)(xh + ks * 32);
      bf16x8 al = *(const bf16x8*)(xl + ks * 32);
      #pragma unroll
      for (int ot = 0; ot < 8; ++ot) {
        bf16x8 bh = *(const bf16x8*)(&WL[0][ks][ot][lane][0]);
        bf16x8 bl = *(const bf16x8*)(&WL[1][ks][ot][lane][0]);
        acc[ot] = __builtin_amdgcn_mfma_f32_16x16x32_bf16(ah, bh, acc[ot], 0, 0, 0);
        acc[ot] = __builtin_amdgcn_mfma_f32_16x16x32_bf16(ah, bl, acc[ot], 0, 0, 0);
        acc[ot] = __builtin_amdgcn_mfma_f32_16x16x32_bf16(al, bh, acc[ot], 0, 0, 0);
      }
    }
    float* hbase = hidden + ((size_t)ry * Nn + n0) * ODIM;
    #pragma unroll
    for (int ot = 0; ot < 8; ++ot) {
      #pragma unroll
      for (int reg = 0; reg < 4; ++reg) {
        int nodeo = lk8 * 4 + reg;
        if (n0 + nodeo < Nn)
          hbase[(size_t)nodeo * ODIM + ot * 16 + lrow] = acc[ot][reg];
      }
    }
  }
}

// ---------------------------------------------------------------------------
// qW projections, emitted directly as split-bf16.
// qwcat row j (j<72: even/A part, j>=72: odd/B part), 128 cols.
// ---------------------------------------------------------------------------
__global__ __launch_bounds__(256) void k_qw(
    const float* __restrict__ W, const float* __restrict__ query,
    unsigned short* __restrict__ qwhi, unsigned short* __restrict__ qwlo,
    int total) {
  int idx = blockIdx.x * 256 + threadIdx.x;
  if (idx >= total) return;
  int d  = idx & 127;
  int rh = idx >> 7;
  int r = rh >> 3, h = rh & 7;
  const float* q  = query + (size_t)rh * DQH;
  const float* Wb = W + ((size_t)r * ODIM + h * 16) * IDIM + d;
  float se = 0.f, so = 0.f;
  #pragma unroll
  for (int j = 0; j < 16; ++j) {
    float wv = Wb[(size_t)j * IDIM];
    se += q[2 * j] * wv;
    so += q[2 * j + 1] * wv;
  }
  unsigned short hse = f2bf(se), hso = f2bf(so);
  qwhi[rh * IDIM + d]        = hse;
  qwlo[rh * IDIM + d]        = f2bf(se - bf2f(hse));
  qwhi[(72 + rh) * IDIM + d] = hso;
  qwlo[(72 + rh) * IDIM + d] = f2bf(so - bf2f(hso));
}

// ---------------------------------------------------------------------------
// MFMA logits pre-pass: [A2|B2][n][j] = x[n][:] . qwcat[j][:]
// B-operand (qwcat, 144x128 hi+lo = 72 KB LDS) staged ONCE, tile-invariant.
// ---------------------------------------------------------------------------
__global__ __launch_bounds__(256) void k_mfma_AB(
    const unsigned short* __restrict__ xhi, const unsigned short* __restrict__ xlo,
    const unsigned short* __restrict__ qwhi, const unsigned short* __restrict__ qwlo,
    float* __restrict__ A2, float* __restrict__ B2, int Nn) {
  __shared__ unsigned short WL[2][4][9][64][8];  // 73728 B (gfx950 LDS > 64 KB ok)
  const int t = threadIdx.x;
  for (int idx = t; idx < 2 * 4 * 9 * 64; idx += 256) {
    int half = idx / 2304;
    int rem  = idx % 2304;
    int ks   = rem / 576;
    int rem2 = rem % 576;
    int ot   = rem2 >> 6;
    int ln   = rem2 & 63;
    int j    = ot * 16 + (ln & 15);
    int kcol = ks * 32 + (ln >> 4) * 8;
    const unsigned short* src = (half ? qwlo : qwhi) + (size_t)j * IDIM + kcol;
    *(ulonglong2*)(&WL[half][ks][ot][ln][0]) = *(const ulonglong2*)src;
  }
  __syncthreads();

  const int wave = t >> 6, lane = t & 63;
  const int lrow = lane & 15, lk8 = lane >> 4;

  for (int tile = blockIdx.x; tile * 64 < Nn; tile += GEMM_GX) {
    int n0 = tile * 64 + wave * 16;
    int nrow = n0 + lrow; if (nrow >= Nn) nrow = Nn - 1;
    const unsigned short* xh = xhi + (size_t)nrow * IDIM + lk8 * 8;
    const unsigned short* xl = xlo + (size_t)nrow * IDIM + lk8 * 8;

    f32x4 acc[9] = {};
    #pragma unroll
    for (int ks = 0; ks < 4; ++ks) {
      bf16x8 ah = *(const bf16x8*)(xh + ks * 32);
      bf16x8 al = *(const bf16x8*)(xl + ks * 32);
      #pragma unroll
      for (int ot = 0; ot < 9; ++ot) {
        bf16x8 bh = *(const bf16x8*)(&WL[0][ks][ot][lane][0]);
        bf16x8 bl = *(const bf16x8*)(&WL[1][ks][ot][lane][0]);
        acc[ot] = __builtin_amdgcn_mfma_f32_16x16x32_bf16(ah, bh, acc[ot], 0, 0, 0);
        acc[ot] = __builtin_amdgcn_mfma_f32_16x16x32_bf16(ah, bl, acc[ot], 0, 0, 0);
        acc[ot] = __builtin_amdgcn_mfma_f32_16x16x32_bf16(al, bh, acc[ot], 0, 0, 0);
      }
    }
    // C/D: col j = ot*16 + (lane&15), row node = (lane>>4)*4 + reg
    #pragma unroll
    for (int ot = 0; ot < 9; ++ot) {
      int j = ot * 16 + lrow;
      #pragma unroll
      for (int reg = 0; reg < 4; ++reg) {
        int nn = n0 + lk8 * 4 + reg;
        if (nn < Nn) {
          float* p = (j < 72) ? (A2 + (size_t)nn * 72 + j)
                              : (B2 + (size_t)nn * 72 + (j - 72));
          *p = acc[ot][reg];
        }
      }
    }
  }
}

// ---------------------------------------------------------------------------
// zero out / deg / cursor (ws is poisoned 0xAA before each replay)
// ---------------------------------------------------------------------------
__global__ __launch_bounds__(256) void k_init(
    float* __restrict__ out, int* __restrict__ deg, int* __restrict__ cursor,
    int N) {
  int tid = blockIdx.x * 256 + threadIdx.x;
  if (tid < N * ODIM) out[tid] = 0.f;
  if (tid < N) { deg[tid] = 0; cursor[tid] = 0; }
}

// ---------------------------------------------------------------------------
// CSR step 1: in-degree count (real edges only)
// ---------------------------------------------------------------------------
__global__ __launch_bounds__(256) void k_deg(
    const int* __restrict__ el, int* __restrict__ deg, int E) {
  int e = blockIdx.x * 256 + threadIdx.x;
  if (e >= E) return;
  atomicAdd(&deg[el[3 * e + 1]], 1);
}

// ---------------------------------------------------------------------------
// CSR step 2: exclusive prefix scan over deg -> off[0..N]  (single block)
// ---------------------------------------------------------------------------
__global__ __launch_bounds__(256) void k_scan(
    const int* __restrict__ deg, int* __restrict__ off, int N) {
  __shared__ int sums[256];
  __shared__ int pref[257];
  const int t = threadIdx.x;
  const int C = (N + 255) / 256;
  const int lo = t * C, hi = min(N, lo + C);
  int s = 0;
  for (int i = lo; i < hi; ++i) s += deg[i];
  sums[t] = s;
  __syncthreads();
  if (t == 0) {
    int run = 0;
    for (int i = 0; i < 256; ++i) { pref[i] = run; run += sums[i]; }
    pref[256] = run;
  }
  __syncthreads();
  int run = pref[t];
  for (int i = lo; i < hi; ++i) { off[i] = run; run += deg[i]; }
  if (lo < N && hi == N) off[N] = run;
}

// ---------------------------------------------------------------------------
// CSR step 3: fill slots; spacked = s | (r<<20); ewp[slot] = edge weight
// ---------------------------------------------------------------------------
__global__ __launch_bounds__(256) void k_fill(
    const int* __restrict__ el, const float* __restrict__ ew,
    const int* __restrict__ off, int* __restrict__ cursor,
    int* __restrict__ spacked, float* __restrict__ ewp, int E) {
  int e = blockIdx.x * 256 + threadIdx.x;
  if (e >= E) return;
  int s = el[3 * e], d = el[3 * e + 1], r = el[3 * e + 2];
  int slot = off[d] + atomicAdd(&cursor[d], 1);
  spacked[slot] = s | (r << 20);
  ewp[slot] = ew[e];
}

// ---------------------------------------------------------------------------
// segment max + sum + attw, atomic-free. One wave per dst (4 dst/block).
// node-major A2/B2: w = leaky(A2[s][r*8+h] + B2[d][r*8+h])
// ---------------------------------------------------------------------------
__global__ __launch_bounds__(256) void k_seg(
    const int* __restrict__ off, const int* __restrict__ spacked,
    const float* __restrict__ ewp, const float* __restrict__ A2,
    const float* __restrict__ B2, float* __restrict__ attw,
    float* __restrict__ scale, int E, int N, int selfRel) {
  const int d = blockIdx.x * 4 + (threadIdx.x >> 6);
  if (d >= N) return;
  const int lane = threadIdx.x & 63;
  const int jg = lane >> 3, h = lane & 7;
  const int base = off[d];
  const int degd = off[d + 1] - base;
  const int nslots = degd + 1;           // + self-loop

  // pass 1: max of leaky(A2[s][r8+h] + B2[d][r8+h])
  float m = -3.4e38f;
  for (int j = jg; j < nslots; j += 8) {
    int s, r;
    if (j < degd) { int sp = spacked[base + j]; s = sp & 0xFFFFF; r = sp >> 20; }
    else          { s = d; r = selfRel; }
    float w = leaky(A2[(size_t)s * 72 + r * 8 + h] + B2[(size_t)d * 72 + r * 8 + h]);
    m = fmaxf(m, w);
  }
  m = fmaxf(m, __shfl_xor(m, 8));
  m = fmaxf(m, __shfl_xor(m, 16));
  m = fmaxf(m, __shfl_xor(m, 32));

  // pass 2: attw = exp(w - m)*ew ; sum
  float sum = 0.f;
  for (int j = jg; j < nslots; j += 8) {
    int s, r; float ewv; size_t aslot;
    if (j < degd) {
      int sp = spacked[base + j]; s = sp & 0xFFFFF; r = sp >> 20;
      ewv = ewp[base + j]; aslot = (size_t)(base + j);
    } else {
      s = d; r = selfRel; ewv = 1.0f; aslot = (size_t)E + d;
    }
    float w = leaky(A2[(size_t)s * 72 + r * 8 + h] + B2[(size_t)d * 72 + r * 8 + h]);
    float att = expf(w - m) * ewv;
    attw[aslot * NH + h] = att;
    sum += att;
  }
  sum += __shfl_xor(sum, 8);
  sum += __shfl_xor(sum, 16);
  sum += __shfl_xor(sum, 32);

  if (jg == 0)
    scale[(size_t)d * NH + h] = 1.0f / (sum / (float)nslots + EPSV);
}

// ---------------------------------------------------------------------------
// gather: one block (4 waves) per dst node. No atomics.
// ---------------------------------------------------------------------------
__global__ __launch_bounds__(256) void k_gather(
    const int* __restrict__ off, const int* __restrict__ spacked,
    const float* __restrict__ attw, const float* __restrict__ scale,
    const float* __restrict__ hidden, float* __restrict__ out,
    int E, int N, int selfRel, int r0, int r1) {
  const int d = blockIdx.x;
  const int t = threadIdx.x;
  const int wave = t >> 6, lane = t & 63;
  const int base = off[d];
  const int degd = off[d + 1] - base;
  const int hasSelf = (selfRel >= r0 && selfRel < r1) ? 1 : 0;
  const int nslots = degd + hasSelf;
  const int h = lane >> 3;  // head for both float2 components (o = lane*2, +1)
  const float sc = scale[(size_t)d * NH + h];

  float ax = 0.f, ay = 0.f;
  for (int j = wave; j < nslots; j += 4) {
    int s, r; size_t aslot;
    if (j < degd) {
      int sp = spacked[base + j];
      s = sp & 0xFFFFF; r = sp >> 20;
      if (r < r0 || r >= r1) continue;
      aslot = (size_t)(base + j);
    } else {
      s = d; r = selfRel;
      aslot = (size_t)E + d;
    }
    float av = attw[aslot * NH + h] * sc;
    const float2 hv = *(const float2*)(hidden + (((size_t)(r - r0) * N + s) << 7) + lane * 2);
    ax += av * hv.x;
    ay += av * hv.y;
  }

  __shared__ float part[4][128];
  part[wave][lane * 2]     = ax;
  part[wave][lane * 2 + 1] = ay;
  __syncthreads();
  if (t < 128) {
    float s = part[0][t] + part[1][t] + part[2][t] + part[3][t];
    out[((size_t)d << 7) + t] += s;
  }
}

// ---------------------------------------------------------------------------
// out = relu(out / cnt), cnt = deg+1 from CSR offsets
// ---------------------------------------------------------------------------
__global__ __launch_bounds__(256) void k_fin(
    float* __restrict__ out, const int* __restrict__ off, int total) {
  int tid = blockIdx.x * 256 + threadIdx.x;
  if (tid >= total) return;
  int n = tid >> 7;
  float c = (float)(off[n + 1] - off[n] + 1);
  float v = out[tid] / c;
  out[tid] = v > 0.f ? v : 0.f;
}

extern "C" void kernel_launch(void* const* d_in, const int* in_sizes, int n_in,
                              void* d_out, int out_size, void* d_ws, size_t ws_size,
                              hipStream_t stream) {
  const float* x     = (const float*)d_in[0];
  const int*   el    = (const int*)d_in[1];
  const float* ew    = (const float*)d_in[2];
  const float* W     = (const float*)d_in[3];
  const float* query = (const float*)d_in[4];
  const int N    = in_sizes[0] / IDIM;
  const int E    = in_sizes[1] / 3;
  const int Rp1  = in_sizes[3] / (ODIM * IDIM);
  const int Etot = E + N;
  const int selfRel = Rp1 - 1;
  float* out = (float*)d_out;

  // ---- workspace carve-up (ws_size-adaptive) ----
  auto align256 = [](size_t v) { return (v + 255) & ~(size_t)255; };
  char* ws = (char*)d_ws;
  size_t off_b = 0;
  const size_t ab_bytes    = align256((size_t)N * 72 * 4);
  const size_t qw_bytes    = align256((size_t)144 * IDIM * 2);
  const size_t xb_bytes    = align256((size_t)N * IDIM * 2);
  const size_t wb_bytes    = align256((size_t)Rp1 * ODIM * IDIM * 2);
  const size_t int_bytes   = align256((size_t)(N + 1) * 4);
  const size_t slot_bytes  = align256((size_t)E * 4);
  const size_t attw_bytes  = align256((size_t)Etot * NH * 4);
  const size_t scale_bytes = align256((size_t)N * NH * 4);
  const size_t per_rel     = (size_t)N * ODIM * 4;

  float*    A2      = (float*)(ws + off_b);    off_b += ab_bytes;
  float*    B2      = (float*)(ws + off_b);    off_b += ab_bytes;
  unsigned short* qwhi = (unsigned short*)(ws + off_b); off_b += qw_bytes;
  unsigned short* qwlo = (unsigned short*)(ws + off_b); off_b += qw_bytes;
  unsigned short* xhi = (unsigned short*)(ws + off_b); off_b += xb_bytes;
  unsigned short* xlo = (unsigned short*)(ws + off_b); off_b += xb_bytes;
  unsigned short* whi = (unsigned short*)(ws + off_b); off_b += wb_bytes;
  unsigned short* wlo = (unsigned short*)(ws + off_b); off_b += wb_bytes;
  int*      deg     = (int*)(ws + off_b);      off_b += int_bytes;
  int*      csroff  = (int*)(ws + off_b);      off_b += int_bytes;
  int*      cursor  = (int*)(ws + off_b);      off_b += int_bytes;
  int*      spacked = (int*)(ws + off_b);      off_b += slot_bytes;
  float*    ewp     = (float*)(ws + off_b);    off_b += slot_bytes;
  float*    attw    = (float*)(ws + off_b);    off_b += attw_bytes;
  float*    scale   = (float*)(ws + off_b);    off_b += scale_bytes;
  float*    hidden  = (float*)(ws + off_b);    // chunk buffer, RC relations

  int RC = 1;
  if (ws_size > off_b + per_rel) {
    size_t fit = (ws_size - off_b) / per_rel;
    RC = (int)(fit < (size_t)Rp1 ? fit : (size_t)Rp1);
    if (RC < 1) RC = 1;
  }

  // ---- launches ----
  k_init<<<(N * ODIM + 255) / 256, 256, 0, stream>>>(out, deg, cursor, N);
  k_deg<<<(E + 255) / 256, 256, 0, stream>>>(el, deg, E);
  k_scan<<<1, 256, 0, stream>>>(deg, csroff, N);
  k_fill<<<(E + 255) / 256, 256, 0, stream>>>(el, ew, csroff, cursor,
                                              spacked, ewp, E);

  int x4 = N * IDIM / 4;
  k_cvt<<<(x4 + 255) / 256, 256, 0, stream>>>(x, (ushort4*)xhi, (ushort4*)xlo, x4);
  int w4 = Rp1 * ODIM * IDIM / 4;
  k_cvt<<<(w4 + 255) / 256, 256, 0, stream>>>(W, (ushort4*)whi, (ushort4*)wlo, w4);

  int qw_total = 72 * IDIM;
  k_qw<<<(qw_total + 255) / 256, 256, 0, stream>>>(W, query, qwhi, qwlo, qw_total);
  k_mfma_AB<<<GEMM_GX, 256, 0, stream>>>(xhi, xlo, qwhi, qwlo, A2, B2, N);

  k_seg<<<(N + 3) / 4, 256, 0, stream>>>(csroff, spacked, ewp, A2, B2, attw, scale,
                                         E, N, selfRel);

  for (int r0 = 0; r0 < Rp1; r0 += RC) {
    int rc = (r0 + RC <= Rp1) ? RC : (Rp1 - r0);
    dim3 gh(GEMM_GX, rc);
    k_mfma_hidden<<<gh, 256, 0, stream>>>(xhi, xlo, whi, wlo, hidden, N, r0);
    k_gather<<<N, 256, 0, stream>>>(csroff, spacked, attw, scale, hidden, out,
                                    E, N, selfRel, r0, r0 + rc);
  }
  k_fin<<<(N * ODIM + 255) / 256, 256, 0, stream>>>(out, csroff, N * ODIM);
}